// Round 1
// baseline (424.207 us; speedup 1.0000x reference)
//
#include <hip/hip_runtime.h>

typedef unsigned int u32;
typedef unsigned short u16;
using s16x8 = __attribute__((ext_vector_type(8))) short;   // 8 bf16 (4 VGPRs)
using f32x4 = __attribute__((ext_vector_type(4))) float;

static constexpr int NB = 512;     // batch (clouds)
static constexpr int L  = 512;     // points per cloud
static constexpr int F  = 64;      // input features
static constexpr int H  = 128;     // hidden features
static constexpr float EPS = 1e-5f;
static const size_t NTOT = (size_t)NB * L * 2 * H;   // g tail offset in out

// round-to-nearest-even fp32 -> bf16 bits
__device__ __forceinline__ u32 bf_rne(float f) {
    u32 u = __float_as_uint(f);
    return (u + 0x7fffu + ((u >> 16) & 1u)) >> 16;
}

// ---------------------------------------------------------------------------
// Fused kernel: one block per cloud n. 512 threads = 8 waves; each wave owns
// 4 slabs of 16 rows (8 waves x 4 slabs x 16 = 512 rows).
// Phase 1 (per slab): split-bf16 MFMA GEMM (x W^T) -> +bias -> LayerNorm ->
//   ReLU -> y-store; thread-local masked max accumulated across slabs.
// Phase 2: block-local max reduce (shfl + LDS) -> g store (no atomics, no k0)
//   -> broadcast g into the second half of all 512 rows (no k2).
// W converted once per block into bf16 hi/lo B-fragments in LDS (frag-ordered,
// conflict-free ds_read_b128). x: global->register A-fragments, no LDS.
// ---------------------------------------------------------------------------
__global__ __launch_bounds__(512, 4)
void k_fused(const float* __restrict__ xp, const int* __restrict__ maskp,
             const float* __restrict__ Wp, const float* __restrict__ bp,
             const float* __restrict__ gp, const float* __restrict__ betap,
             float* __restrict__ outp)
{
    __shared__ u16  whi[8192];     // 16 KB: B-frag-ordered W hi
    __shared__ u16  wlo[8192];     // 16 KB: B-frag-ordered W lo
    __shared__ float gsh[8][H];    // per-wave masked-max partials
    __shared__ float gfin[H];      // final per-cloud g

    const int n    = blockIdx.x;
    const int tid  = threadIdx.x;
    const int w    = tid >> 6;     // wave 0..7
    const int lane = tid & 63;
    const int m    = lane & 15;
    const int q    = lane >> 4;

    // ---- stage W as bf16 hi/lo fragments. Group g (0..1023) = frag (t,s) x lane:
    //      t=g>>7, s=(g>>6)&1, ln=g&63; element j: W[t*16+(ln&15)][s*32+(ln>>4)*8+j]
    #pragma unroll
    for (int it = 0; it < 2; ++it) {
        const int g  = it * 512 + tid;
        const int t  = g >> 7;
        const int s  = (g >> 6) & 1;
        const int ln = g & 63;
        const int mm = ln & 15;
        const int qq = ln >> 4;
        const float* src = Wp + (t * 16 + mm) * F + s * 32 + qq * 8;
        const float4 a = *(const float4*)src;
        const float4 b = *(const float4*)(src + 4);
        const float xv[8] = {a.x, a.y, a.z, a.w, b.x, b.y, b.z, b.w};
        u32 hi[8], lo[8];
        #pragma unroll
        for (int j = 0; j < 8; ++j) {
            hi[j] = bf_rne(xv[j]);
            const float hf = __uint_as_float(hi[j] << 16);
            lo[j] = bf_rne(xv[j] - hf);
        }
        uint4 ph, pl;
        ph.x = hi[0] | (hi[1] << 16); ph.y = hi[2] | (hi[3] << 16);
        ph.z = hi[4] | (hi[5] << 16); ph.w = hi[6] | (hi[7] << 16);
        pl.x = lo[0] | (lo[1] << 16); pl.y = lo[2] | (lo[3] << 16);
        pl.z = lo[4] | (lo[5] << 16); pl.w = lo[6] | (lo[7] << 16);
        *(uint4*)&whi[g * 8] = ph;
        *(uint4*)&wlo[g * 8] = pl;
    }

    float gmax[8] = {0.f, 0.f, 0.f, 0.f, 0.f, 0.f, 0.f, 0.f};

    __syncthreads();

    // ---- phase 1: 4 slabs of 16 rows per wave
    #pragma unroll 1
    for (int sl = 0; sl < 4; ++sl) {
        const int rb = n * L + (sl * 8 + w) * 16;

        // A fragments: x rows rb..rb+15, split hi/lo (global -> regs, no LDS)
        s16x8 Ahi[2], Alo[2];
        #pragma unroll
        for (int s = 0; s < 2; ++s) {
            const float* xs = xp + (size_t)(rb + m) * F + s * 32 + q * 8;
            const float4 a = *(const float4*)xs;
            const float4 b = *(const float4*)(xs + 4);
            const float xv[8] = {a.x, a.y, a.z, a.w, b.x, b.y, b.z, b.w};
            #pragma unroll
            for (int j = 0; j < 8; ++j) {
                const u32 hb = bf_rne(xv[j]);
                const float hf = __uint_as_float(hb << 16);
                Ahi[s][j] = (short)hb;
                Alo[s][j] = (short)bf_rne(xv[j] - hf);
            }
        }

        // MFMA: 8 h-tiles x 2 k-steps x 3 split terms
        f32x4 acc[8] = {};
        #pragma unroll
        for (int t = 0; t < 8; ++t) {
            #pragma unroll
            for (int s = 0; s < 2; ++s) {
                const s16x8 Bh = *(const s16x8*)&whi[((t * 2 + s) * 64 + lane) * 8];
                const s16x8 Bl = *(const s16x8*)&wlo[((t * 2 + s) * 64 + lane) * 8];
                acc[t] = __builtin_amdgcn_mfma_f32_16x16x32_bf16(Ahi[s], Bh, acc[t], 0, 0, 0);
                acc[t] = __builtin_amdgcn_mfma_f32_16x16x32_bf16(Alo[s], Bh, acc[t], 0, 0, 0);
                acc[t] = __builtin_amdgcn_mfma_f32_16x16x32_bf16(Ahi[s], Bl, acc[t], 0, 0, 0);
            }
        }

        // per-column params (h = t*16 + m); L1/L2-hot scalar loads
        float bias[8], gam[8], bet[8];
        #pragma unroll
        for (int t = 0; t < 8; ++t) {
            const int h = t * 16 + m;
            bias[t] = bp[h];
            gam[t]  = gp[h];
            bet[t]  = betap[h];
        }
        #pragma unroll
        for (int t = 0; t < 8; ++t)
            #pragma unroll
            for (int r = 0; r < 4; ++r)
                acc[t][r] += bias[t];

        // LayerNorm stats. C/D layout: col=lane&15, row=q*4+reg.
        float sum[4] = {0, 0, 0, 0}, sq[4] = {0, 0, 0, 0};
        #pragma unroll
        for (int t = 0; t < 8; ++t)
            #pragma unroll
            for (int r = 0; r < 4; ++r) {
                const float v = acc[t][r];
                sum[r] += v; sq[r] += v * v;
            }
        #pragma unroll
        for (int r = 0; r < 4; ++r) {
            #pragma unroll
            for (int o = 1; o < 16; o <<= 1) {
                sum[r] += __shfl_xor(sum[r], o);
                sq[r]  += __shfl_xor(sq[r],  o);
            }
        }
        float mu[4], rs[4];
        #pragma unroll
        for (int r = 0; r < 4; ++r) {
            mu[r] = sum[r] * (1.0f / 128.0f);
            const float var = sq[r] * (1.0f / 128.0f) - mu[r] * mu[r];
            rs[r] = rsqrtf(var + EPS);
        }

        int mk[4];
        #pragma unroll
        for (int r = 0; r < 4; ++r) mk[r] = maskp[rb + q * 4 + r];

        // normalize, relu, store y (64B-aligned quad segments), masked max
        #pragma unroll
        for (int t = 0; t < 8; ++t) {
            #pragma unroll
            for (int r = 0; r < 4; ++r) {
                float y = (acc[t][r] - mu[r]) * rs[r] * gam[t] + bet[t];
                y = fmaxf(y, 0.0f);
                outp[(size_t)(rb + q * 4 + r) * (2 * H) + t * 16 + m] = y;
                if (mk[r] != 0) gmax[t] = fmaxf(gmax[t], y);
            }
        }
    }

    // ---- phase 2a: reduce gmax over q-groups (rows), then across waves
    #pragma unroll
    for (int t = 0; t < 8; ++t) {
        float gmv = gmax[t];
        gmv = fmaxf(gmv, __shfl_xor(gmv, 16));
        gmv = fmaxf(gmv, __shfl_xor(gmv, 32));
        if (q == 0) gsh[w][t * 16 + m] = gmv;
    }
    __syncthreads();

    if (tid < H) {
        float mx = gsh[0][tid];
        #pragma unroll
        for (int ww = 1; ww < 8; ++ww) mx = fmaxf(mx, gsh[ww][tid]);
        gfin[tid] = mx;
        outp[NTOT + (size_t)n * H + tid] = mx;   // direct store, no atomics
    }
    __syncthreads();

    // ---- phase 2b: broadcast g into second half of all 512 rows.
    // lanes tc=0..31 cover 512 contiguous bytes; 16 row-groups via tr.
    const int tc = tid & 31;
    const int tr = tid >> 5;
    const float4 g4 = *(const float4*)&gfin[tc * 4];
    float* dst = outp + (size_t)n * L * (2 * H) + H + tc * 4;
    #pragma unroll
    for (int ri = 0; ri < 32; ++ri) {
        *(float4*)(dst + (size_t)(tr * 32 + ri) * (2 * H)) = g4;
    }
}

extern "C" void kernel_launch(void* const* d_in, const int* in_sizes, int n_in,
                              void* d_out, int out_size, void* d_ws, size_t ws_size,
                              hipStream_t stream)
{
    (void)in_sizes; (void)n_in; (void)out_size; (void)d_ws; (void)ws_size;
    const float* x     = (const float*)d_in[0];
    const int*   mask  = (const int*)d_in[1];
    const float* W     = (const float*)d_in[2];
    const float* b     = (const float*)d_in[3];
    const float* gamma = (const float*)d_in[4];
    const float* beta  = (const float*)d_in[5];
    float* out = (float*)d_out;

    k_fused<<<dim3(NB), dim3(512), 0, stream>>>(x, mask, W, b, gamma, beta, out);
}

// Round 2
// 341.698 us; speedup vs baseline: 1.2415x; 1.2415x over previous
//
#include <hip/hip_runtime.h>

typedef unsigned int u32;
typedef unsigned short u16;
using s16x8 = __attribute__((ext_vector_type(8))) short;   // 8 bf16 (4 VGPRs)
using f32x4 = __attribute__((ext_vector_type(4))) float;

static constexpr int NB = 512;     // batch
static constexpr int L  = 512;     // points per cloud
static constexpr int F  = 64;      // input features
static constexpr int H  = 128;     // hidden features
static constexpr float EPS = 1e-5f;
static const size_t NTOT = (size_t)NB * L * 2 * H;   // g tail offset in out

// round-to-nearest-even fp32 -> bf16 bits
__device__ __forceinline__ u32 bf_rne(float f) {
    u32 u = __float_as_uint(f);
    return (u + 0x7fffu + ((u >> 16) & 1u)) >> 16;
}

// ---------------------------------------------------------------------------
// K0: zero the g tail of out (harness poisons d_out with 0xAA).
// ---------------------------------------------------------------------------
__global__ __launch_bounds__(256)
void k0_init(float* __restrict__ outp)
{
    const int i = blockIdx.x * 256 + threadIdx.x;
    if (i < NB * H) outp[NTOT + i] = 0.0f;
}

// ---------------------------------------------------------------------------
// K1: one block per (cloud n, 64-row chunk); 4 waves, each owning 16 rows.
// Split-bf16 MFMA GEMM (x W^T) -> +bias -> LayerNorm -> ReLU;
// epilogue TRANSPOSES y through LDS so global stores are full contiguous
// 512B row-halves (no partial-line RMW), then per-block masked max ->
// atomicMax into g tail (uint bits, values >= 0).
// LDS: W hi/lo frags (32KB) aliased by the transpose buffer (33KB) after
// MFMA; gsh lives above both. Total 35840B -> 4 blocks/CU.
// ---------------------------------------------------------------------------
__global__ __launch_bounds__(256)
void k1_gemm_ln(const float* __restrict__ xp, const int* __restrict__ maskp,
                const float* __restrict__ Wp, const float* __restrict__ bp,
                const float* __restrict__ gp, const float* __restrict__ betap,
                float* __restrict__ outp)
{
    __shared__ __align__(16) char smem[35840];
    u16*   whi = (u16*)smem;                 // [0, 16384): B-frag W hi
    u16*   wlo = (u16*)(smem + 16384);       // [16384, 32768): B-frag W lo
    float* tb  = (float*)smem;               // [0, 33792): 64 rows x 132 floats
    float* gsh = (float*)(smem + 33792);     // [4][128] per-wave max partials

    const int bx    = blockIdx.x;
    const int n     = bx >> 3;
    const int chunk = bx & 7;
    const int tid   = threadIdx.x;
    const int w     = tid >> 6;
    const int lane  = tid & 63;
    const int m     = lane & 15;
    const int q     = lane >> 4;

    // ---- stage W as bf16 hi/lo fragments. Group g (0..1023) = frag (t,s) x lane:
    //      t=g>>7, s=(g>>6)&1, ln=g&63; element j: W[t*16+(ln&15)][s*32+(ln>>4)*8+j]
    #pragma unroll
    for (int it = 0; it < 4; ++it) {
        const int g  = it * 256 + tid;
        const int t  = g >> 7;
        const int s  = (g >> 6) & 1;
        const int ln = g & 63;
        const int mm = ln & 15;
        const int qq = ln >> 4;
        const float* src = Wp + (t * 16 + mm) * F + s * 32 + qq * 8;
        const float4 a = *(const float4*)src;
        const float4 b = *(const float4*)(src + 4);
        const float xv[8] = {a.x, a.y, a.z, a.w, b.x, b.y, b.z, b.w};
        u32 hi[8], lo[8];
        #pragma unroll
        for (int j = 0; j < 8; ++j) {
            hi[j] = bf_rne(xv[j]);
            const float hf = __uint_as_float(hi[j] << 16);
            lo[j] = bf_rne(xv[j] - hf);
        }
        uint4 ph, pl;
        ph.x = hi[0] | (hi[1] << 16); ph.y = hi[2] | (hi[3] << 16);
        ph.z = hi[4] | (hi[5] << 16); ph.w = hi[6] | (hi[7] << 16);
        pl.x = lo[0] | (lo[1] << 16); pl.y = lo[2] | (lo[3] << 16);
        pl.z = lo[4] | (lo[5] << 16); pl.w = lo[6] | (lo[7] << 16);
        *(uint4*)&whi[g * 8] = ph;
        *(uint4*)&wlo[g * 8] = pl;
    }

    // ---- A fragments: x rows rb..rb+15, split hi/lo (global -> regs, no LDS)
    const int rb = n * L + chunk * 64 + w * 16;
    s16x8 Ahi[2], Alo[2];
    #pragma unroll
    for (int s = 0; s < 2; ++s) {
        const float* xs = xp + (size_t)(rb + m) * F + s * 32 + q * 8;
        const float4 a = *(const float4*)xs;
        const float4 b = *(const float4*)(xs + 4);
        const float xv[8] = {a.x, a.y, a.z, a.w, b.x, b.y, b.z, b.w};
        #pragma unroll
        for (int j = 0; j < 8; ++j) {
            const u32 hb = bf_rne(xv[j]);
            const float hf = __uint_as_float(hb << 16);
            Ahi[s][j] = (short)hb;
            Alo[s][j] = (short)bf_rne(xv[j] - hf);
        }
    }
    __syncthreads();

    // ---- MFMA: 8 h-tiles x 2 k-steps x 3 split terms
    f32x4 acc[8] = {};
    #pragma unroll
    for (int t = 0; t < 8; ++t) {
        #pragma unroll
        for (int s = 0; s < 2; ++s) {
            const s16x8 Bh = *(const s16x8*)&whi[((t * 2 + s) * 64 + lane) * 8];
            const s16x8 Bl = *(const s16x8*)&wlo[((t * 2 + s) * 64 + lane) * 8];
            acc[t] = __builtin_amdgcn_mfma_f32_16x16x32_bf16(Ahi[s], Bh, acc[t], 0, 0, 0);
            acc[t] = __builtin_amdgcn_mfma_f32_16x16x32_bf16(Alo[s], Bh, acc[t], 0, 0, 0);
            acc[t] = __builtin_amdgcn_mfma_f32_16x16x32_bf16(Ahi[s], Bl, acc[t], 0, 0, 0);
        }
    }

    // ---- per-column params (h = t*16 + m); L2/L1-hot scalar loads
    float bias[8], gam[8], bet[8];
    #pragma unroll
    for (int t = 0; t < 8; ++t) {
        const int h = t * 16 + m;
        bias[t] = bp[h];
        gam[t]  = gp[h];
        bet[t]  = betap[h];
    }
    #pragma unroll
    for (int t = 0; t < 8; ++t)
        #pragma unroll
        for (int r = 0; r < 4; ++r)
            acc[t][r] += bias[t];

    // ---- LayerNorm stats. C/D layout: col=lane&15, row=q*4+reg.
    float sum[4] = {0, 0, 0, 0}, sq[4] = {0, 0, 0, 0};
    #pragma unroll
    for (int t = 0; t < 8; ++t)
        #pragma unroll
        for (int r = 0; r < 4; ++r) {
            const float v = acc[t][r];
            sum[r] += v; sq[r] += v * v;
        }
    #pragma unroll
    for (int r = 0; r < 4; ++r) {
        #pragma unroll
        for (int o = 1; o < 16; o <<= 1) {
            sum[r] += __shfl_xor(sum[r], o);
            sq[r]  += __shfl_xor(sq[r],  o);
        }
    }
    float mu[4], rs[4];
    #pragma unroll
    for (int r = 0; r < 4; ++r) {
        mu[r] = sum[r] * (1.0f / 128.0f);
        const float var = sq[r] * (1.0f / 128.0f) - mu[r] * mu[r];
        rs[r] = rsqrtf(var + EPS);
    }

    int mk[4];
    #pragma unroll
    for (int r = 0; r < 4; ++r) mk[r] = maskp[rb + q * 4 + r];

    // ---- normalize, relu -> y in regs; masked max in regs
    float gmax[8];
    #pragma unroll
    for (int t = 0; t < 8; ++t) {
        float gm = 0.0f;
        #pragma unroll
        for (int r = 0; r < 4; ++r) {
            float y = (acc[t][r] - mu[r]) * rs[r] * gam[t] + bet[t];
            y = fmaxf(y, 0.0f);
            acc[t][r] = y;
            if (mk[r] != 0) gm = fmaxf(gm, y);
        }
        gmax[t] = gm;
    }

    // ---- transpose through LDS (whi/wlo are dead for ALL waves after this sync)
    __syncthreads();
    #pragma unroll
    for (int t = 0; t < 8; ++t)
        #pragma unroll
        for (int r = 0; r < 4; ++r)
            tb[(w * 16 + q * 4 + r) * 132 + t * 16 + m] = acc[t][r];
    __syncthreads();

    // ---- store 64 rows x 512B first-halves, fully coalesced:
    // per instruction a wave covers 2 contiguous 512B segments (full lines).
    {
        const int rr0 = tid >> 5;          // 0..7
        const int c   = tid & 31;          // float4 index within row-half
        const size_t growbase = (size_t)n * L + chunk * 64;
        #pragma unroll
        for (int i = 0; i < 8; ++i) {
            const int rr = i * 8 + rr0;
            const float4 v = *(const float4*)&tb[rr * 132 + c * 4];
            *(float4*)(outp + (growbase + rr) * (2 * H) + c * 4) = v;
        }
    }

    // ---- per-wave masked-max partials -> block reduce -> atomicMax to tail
    #pragma unroll
    for (int t = 0; t < 8; ++t) {
        float gm = gmax[t];
        gm = fmaxf(gm, __shfl_xor(gm, 16));
        gm = fmaxf(gm, __shfl_xor(gm, 32));
        if (q == 0) gsh[w * H + t * 16 + m] = gm;
    }
    __syncthreads();
    if (tid < H) {
        const float mx = fmaxf(fmaxf(gsh[0 * H + tid], gsh[1 * H + tid]),
                               fmaxf(gsh[2 * H + tid], gsh[3 * H + tid]));
        atomicMax((u32*)(outp + NTOT + (size_t)n * H + tid), __float_as_uint(mx));
    }
}

// ---------------------------------------------------------------------------
// K2: one block per (n, 64-row chunk): read final g from the out tail
// (L2-hot, 512 B per cloud) and broadcast into the second half of rows.
// ---------------------------------------------------------------------------
__global__ __launch_bounds__(256)
void k2_bcast(float* __restrict__ outp)
{
    const int bx  = blockIdx.x;
    const int n   = bx >> 3;
    const int c2  = bx & 7;
    const int tid = threadIdx.x;
    const int tc  = tid & 31;
    const int tr  = tid >> 5;
    const int h0  = tc * 4;

    const float4 g4 = *(const float4*)(outp + NTOT + (size_t)n * H + h0);

    #pragma unroll
    for (int ri = 0; ri < 8; ++ri) {
        const int l = c2 * 64 + tr * 8 + ri;
        *(float4*)(outp + ((size_t)n * L + l) * (2 * H) + H + h0) = g4;
    }
}

extern "C" void kernel_launch(void* const* d_in, const int* in_sizes, int n_in,
                              void* d_out, int out_size, void* d_ws, size_t ws_size,
                              hipStream_t stream)
{
    (void)in_sizes; (void)n_in; (void)out_size; (void)d_ws; (void)ws_size;
    const float* x     = (const float*)d_in[0];
    const int*   mask  = (const int*)d_in[1];
    const float* W     = (const float*)d_in[2];
    const float* b     = (const float*)d_in[3];
    const float* gamma = (const float*)d_in[4];
    const float* beta  = (const float*)d_in[5];
    float* out = (float*)d_out;

    k0_init<<<dim3((NB * H + 255) / 256), dim3(256), 0, stream>>>(out);
    k1_gemm_ln<<<dim3(NB * 8), dim3(256), 0, stream>>>(
        x, mask, W, b, gamma, beta, out);
    k2_bcast<<<dim3(NB * 8), dim3(256), 0, stream>>>(out);
}